// Round 1
// baseline (586.505 us; speedup 1.0000x reference)
//
#include <hip/hip_runtime.h>

#define B_  2
#define T_  4096
#define D_  512
#define H_  8
#define HD_ 64
#define M_  (B_*T_)   // 8192 rows

typedef short v8s __attribute__((ext_vector_type(8)));
typedef float v4f __attribute__((ext_vector_type(4)));

__device__ __forceinline__ float bf2f(unsigned short u){
  union { unsigned int i; float f; } v; v.i = ((unsigned int)u) << 16; return v.f;
}
__device__ __forceinline__ unsigned short f2bf(float f){
  union { float f; unsigned int u; } v; v.f = f;
  unsigned int r = v.u + 0x7FFFu + ((v.u >> 16) & 1u);
  return (unsigned short)(r >> 16);
}
__device__ __forceinline__ v4f zero4(){ v4f z; z[0]=0.f; z[1]=0.f; z[2]=0.f; z[3]=0.f; return z; }

// ---------------- dtype probe: fp32 inputs -> flag=1, bf16 -> flag=0 ----------------
// fp32 data reinterpreted as bf16 words yields random exponents (values > 1e4 / inf / nan)
// with overwhelming probability over 4096 samples; real bf16 N(0,1) data never does.
__global__ void detect_dtype(const unsigned short* __restrict__ x, int* __restrict__ flag){
  __shared__ int cnt;
  if (threadIdx.x == 0) cnt = 0;
  __syncthreads();
  int bad = 0;
  for (int i = threadIdx.x; i < 4096; i += 256) {
    float v = bf2f(x[i]);
    if (!(fabsf(v) < 1e4f)) bad = 1;   // catches huge / inf / nan
  }
  if (bad) atomicAdd(&cnt, 1);
  __syncthreads();
  if (threadIdx.x == 0) *flag = (cnt > 0) ? 1 : 0;
}

__global__ void conv_bf16(const void* __restrict__ src, unsigned short* __restrict__ dst,
                          int n, const int* __restrict__ flag){
  int i = blockIdx.x * 256 + threadIdx.x;
  if (i >= n) return;
  if (*flag) dst[i] = f2bf(((const float*)src)[i]);
  else       dst[i] = ((const unsigned short*)src)[i];
}

__global__ void conv_f32(const void* __restrict__ src, float* __restrict__ dst,
                         int n, const int* __restrict__ flag){
  int i = blockIdx.x * 256 + threadIdx.x;
  if (i >= n) return;
  dst[i] = (*flag) ? ((const float*)src)[i] : bf2f(((const unsigned short*)src)[i]);
}

// ---------------- GEMM core: Y[M,512] = A[M,512] * W[512,512]^T (bf16, fp32 acc) ------
// 128x128 block tile, 4 waves, each wave 64x64 via 4x4 frags of mfma 16x16x32.
__device__ __forceinline__ void gemm_core(const unsigned short* __restrict__ A,
                                          const unsigned short* __restrict__ W,
                                          int m0, int n0, v4f acc[4][4]) {
  const int lane = threadIdx.x & 63;
  const int wid  = threadIdx.x >> 6;
  const int r = lane & 15, q = lane >> 4;
  const int wm = m0 + (wid & 1) * 64;
  const int wn = n0 + (wid >> 1) * 64;
#pragma unroll
  for (int i = 0; i < 4; i++)
#pragma unroll
    for (int j = 0; j < 4; j++) acc[i][j] = zero4();
  for (int kk = 0; kk < D_; kk += 32) {
    v8s a[4], b[4];
#pragma unroll
    for (int i = 0; i < 4; i++)
      a[i] = *(const v8s*)(A + (size_t)(wm + i*16 + r) * D_ + kk + q*8);
#pragma unroll
    for (int j = 0; j < 4; j++)
      b[j] = *(const v8s*)(W + (size_t)(wn + j*16 + r) * D_ + kk + q*8);
#pragma unroll
    for (int i = 0; i < 4; i++)
#pragma unroll
      for (int j = 0; j < 4; j++)
        acc[i][j] = __builtin_amdgcn_mfma_f32_16x16x32_bf16(a[i], b[j], acc[i][j], 0, 0, 0);
  }
}

__global__ __launch_bounds__(256) void gemm_qkv(
    const unsigned short* __restrict__ X,
    const unsigned short* __restrict__ Wq, const unsigned short* __restrict__ Wk,
    const unsigned short* __restrict__ Wv,
    unsigned short* __restrict__ Qo, unsigned short* __restrict__ Ko,
    unsigned short* __restrict__ Vo)
{
  const unsigned short* W = (blockIdx.z == 0) ? Wq : (blockIdx.z == 1 ? Wk : Wv);
  unsigned short* Y       = (blockIdx.z == 0) ? Qo : (blockIdx.z == 1 ? Ko : Vo);
  const int m0 = blockIdx.x * 128, n0 = blockIdx.y * 128;
  v4f acc[4][4];
  gemm_core(X, W, m0, n0, acc);
  const int lane = threadIdx.x & 63, wid = threadIdx.x >> 6;
  const int r = lane & 15, q = lane >> 4;
  const int wm = m0 + (wid & 1) * 64, wn = n0 + (wid >> 1) * 64;
#pragma unroll
  for (int i = 0; i < 4; i++)
#pragma unroll
    for (int j = 0; j < 4; j++)
#pragma unroll
      for (int rr = 0; rr < 4; rr++)
        Y[(size_t)(wm + i*16 + q*4 + rr) * D_ + wn + j*16 + r] = f2bf(acc[i][j][rr]);
}

__global__ __launch_bounds__(256) void gemm_out(
    const unsigned short* __restrict__ A, const unsigned short* __restrict__ W,
    const float* __restrict__ bias, void* __restrict__ out, const int* __restrict__ flagp)
{
  const int m0 = blockIdx.x * 128, n0 = blockIdx.y * 128;
  v4f acc[4][4];
  gemm_core(A, W, m0, n0, acc);
  const int lane = threadIdx.x & 63, wid = threadIdx.x >> 6;
  const int r = lane & 15, q = lane >> 4;
  const int wm = m0 + (wid & 1) * 64, wn = n0 + (wid >> 1) * 64;
  const int flag = *flagp;
#pragma unroll
  for (int i = 0; i < 4; i++)
#pragma unroll
    for (int j = 0; j < 4; j++)
#pragma unroll
      for (int rr = 0; rr < 4; rr++) {
        const int row = wm + i*16 + q*4 + rr;
        const int col = wn + j*16 + r;
        const float v = acc[i][j][rr] + bias[col];
        if (flag) ((float*)out)[(size_t)row * D_ + col] = v;
        else ((unsigned short*)out)[(size_t)row * D_ + col] = f2bf(v);
      }
}

// ---------------- flash attention, causal, one head-slice per block --------------------
// Block: 64 q-rows (4 waves x 16). k-tiles of 32. V staged transposed in LDS (shared),
// P transposed per-wave through LDS (C/D layout -> A layout).
__global__ __launch_bounds__(256) void attn_kernel(
    const unsigned short* __restrict__ Q,
    const unsigned short* __restrict__ K,
    const unsigned short* __restrict__ V,
    unsigned short* __restrict__ Ctx)
{
  const int b = blockIdx.z, h = blockIdx.y;
  const int q0 = blockIdx.x * 64;
  const int tid = threadIdx.x;
  const int lane = tid & 63, wid = tid >> 6;
  const int r = lane & 15, quad = lane >> 4;

  const size_t headoff = (size_t)b * T_ * D_ + (size_t)h * HD_;
  const unsigned short* Qh = Q + headoff;
  const unsigned short* Kh = K + headoff;
  const unsigned short* Vh = V + headoff;
  unsigned short* Ch = Ctx + headoff;

  __shared__ unsigned short VT[64][40];     // V^T: [hd][kv], stride 40 -> 2-way (free)
  __shared__ unsigned short PT[4][16][40];  // per-wave P: [q][kv]

  const int qrow = q0 + wid * 16;
  const v8s aq0 = *(const v8s*)(Qh + (size_t)(qrow + r) * D_ + quad * 8);
  const v8s aq1 = *(const v8s*)(Qh + (size_t)(qrow + r) * D_ + 32 + quad * 8);

  v4f o[4];
#pragma unroll
  for (int j = 0; j < 4; j++) o[j] = zero4();
  float mrow[4], lrow[4];
#pragma unroll
  for (int rr = 0; rr < 4; rr++) { mrow[rr] = -1e30f; lrow[rr] = 0.f; }

  const int ntiles = (q0 + 64) >> 5;
  const int vkv = tid >> 3;          // 0..31
  const int vhd = (tid & 7) * 8;     // 0,8,..,56

  for (int kt = 0; kt < ntiles; ++kt) {
    const int kb = kt << 5;
    __syncthreads();                 // protect VT from previous iteration's readers
    {                                // cooperative V^T staging: 32 kv x 64 hd
      v8s vv = *(const v8s*)(Vh + (size_t)(kb + vkv) * D_ + vhd);
#pragma unroll
      for (int j = 0; j < 8; j++) VT[vhd + j][vkv] = (unsigned short)vv[j];
    }
    __syncthreads();
    if (kb <= qrow + 15) {           // wave-level causal skip (kb%32, qrow%16 => kb<=qrow)
      v4f s0 = zero4(), s1 = zero4();
      {
        v8s k00 = *(const v8s*)(Kh + (size_t)(kb + r) * D_ + quad * 8);
        v8s k01 = *(const v8s*)(Kh + (size_t)(kb + r) * D_ + 32 + quad * 8);
        v8s k10 = *(const v8s*)(Kh + (size_t)(kb + 16 + r) * D_ + quad * 8);
        v8s k11 = *(const v8s*)(Kh + (size_t)(kb + 16 + r) * D_ + 32 + quad * 8);
        s0 = __builtin_amdgcn_mfma_f32_16x16x32_bf16(aq0, k00, s0, 0, 0, 0);
        s0 = __builtin_amdgcn_mfma_f32_16x16x32_bf16(aq1, k01, s0, 0, 0, 0);
        s1 = __builtin_amdgcn_mfma_f32_16x16x32_bf16(aq0, k10, s1, 0, 0, 0);
        s1 = __builtin_amdgcn_mfma_f32_16x16x32_bf16(aq1, k11, s1, 0, 0, 0);
      }
      const int kv0 = kb + r, kv1 = kb + 16 + r;
#pragma unroll
      for (int rr = 0; rr < 4; rr++) {
        const int qq = qrow + quad * 4 + rr;
        float sc0 = (kv0 <= qq) ? s0[rr] * 0.125f : -1e30f;
        float sc1 = (kv1 <= qq) ? s1[rr] * 0.125f : -1e30f;
        float t = fmaxf(sc0, sc1);
        t = fmaxf(t, __shfl_xor(t, 1, 64));
        t = fmaxf(t, __shfl_xor(t, 2, 64));
        t = fmaxf(t, __shfl_xor(t, 4, 64));
        t = fmaxf(t, __shfl_xor(t, 8, 64));
        const float mnew = fmaxf(mrow[rr], t);
        const float alpha = __expf(mrow[rr] - mnew);
        mrow[rr] = mnew;
        const float p0 = __expf(sc0 - mnew);   // masked lanes underflow to 0
        const float p1 = __expf(sc1 - mnew);
        float rs = p0 + p1;
        rs += __shfl_xor(rs, 1, 64);
        rs += __shfl_xor(rs, 2, 64);
        rs += __shfl_xor(rs, 4, 64);
        rs += __shfl_xor(rs, 8, 64);
        lrow[rr] = lrow[rr] * alpha + rs;
        o[0][rr] *= alpha; o[1][rr] *= alpha; o[2][rr] *= alpha; o[3][rr] *= alpha;
        PT[wid][quad * 4 + rr][r]      = f2bf(p0);
        PT[wid][quad * 4 + rr][16 + r] = f2bf(p1);
      }
      asm volatile("s_waitcnt lgkmcnt(0)" ::: "memory");  // PT write->read, same wave
      const v8s pf = *(const v8s*)(&PT[wid][r][quad * 8]);
#pragma unroll
      for (int j = 0; j < 4; j++) {
        v8s vf = *(const v8s*)(&VT[j * 16 + r][quad * 8]);
        o[j] = __builtin_amdgcn_mfma_f32_16x16x32_bf16(pf, vf, o[j], 0, 0, 0);
      }
    }
  }
#pragma unroll
  for (int rr = 0; rr < 4; rr++) {
    const float inv = 1.0f / lrow[rr];
    const size_t row = (size_t)(qrow + quad * 4 + rr) * D_;
#pragma unroll
    for (int j = 0; j < 4; j++)
      Ch[row + j * 16 + r] = f2bf(o[j][rr] * inv);
  }
}

// ---------------- launch ----------------
extern "C" void kernel_launch(void* const* d_in, const int* in_sizes, int n_in,
                              void* d_out, int out_size, void* d_ws, size_t ws_size,
                              hipStream_t stream) {
  char* ws = (char*)d_ws;
  unsigned short* xb  = (unsigned short*)(ws + 0);              // 8 MiB
  unsigned short* qb  = (unsigned short*)(ws + 8388608);        // 8 MiB
  unsigned short* kb  = (unsigned short*)(ws + 16777216);       // 8 MiB
  unsigned short* vb  = (unsigned short*)(ws + 25165824);       // 8 MiB
  unsigned short* ctx = (unsigned short*)(ws + 33554432);       // 8 MiB
  unsigned short* wqb = (unsigned short*)(ws + 41943040);       // 512 KiB each
  unsigned short* wkb = (unsigned short*)(ws + 41943040 + 524288);
  unsigned short* wvb = (unsigned short*)(ws + 41943040 + 2 * 524288);
  unsigned short* wob = (unsigned short*)(ws + 41943040 + 3 * 524288);
  float*          bof = (float*)(ws + 41943040 + 4 * 524288);
  int*           flag = (int*)(ws + 41943040 + 4 * 524288 + 4096);

  detect_dtype<<<1, 256, 0, stream>>>((const unsigned short*)d_in[0], flag);

  const int nx = M_ * D_;    // 4,194,304
  const int nw = D_ * D_;    // 262,144
  conv_bf16<<<(nx + 255) / 256, 256, 0, stream>>>(d_in[0], xb, nx, flag);
  conv_bf16<<<(nw + 255) / 256, 256, 0, stream>>>(d_in[1], wqb, nw, flag);
  conv_bf16<<<(nw + 255) / 256, 256, 0, stream>>>(d_in[2], wkb, nw, flag);
  conv_bf16<<<(nw + 255) / 256, 256, 0, stream>>>(d_in[3], wvb, nw, flag);
  conv_bf16<<<(nw + 255) / 256, 256, 0, stream>>>(d_in[4], wob, nw, flag);
  conv_f32<<<2, 256, 0, stream>>>(d_in[5], bof, D_, flag);

  gemm_qkv<<<dim3(M_ / 128, D_ / 128, 3), 256, 0, stream>>>(xb, wqb, wkb, wvb, qb, kb, vb);
  attn_kernel<<<dim3(T_ / 64, H_, B_), 256, 0, stream>>>(qb, kb, vb, ctx);
  gemm_out<<<dim3(M_ / 128, D_ / 128, 1), 256, 0, stream>>>(ctx, wob, bof, d_out, flag);
}